// Round 4
// baseline (280.817 us; speedup 1.0000x reference)
//
#include <hip/hip_runtime.h>

// FromRGB fused pipeline:
//   x[8,16,512,512] --(IHT up2 + blur down2 + Haar down2 composed into one
//   separable 4x4 stride-2 stencil)--> new_in[8,16,256,256]
//   new_in --(1x1 conv 16->512, scale 0.25, +bias, leakyrelu(0.2)*sqrt2)--> out[8,512,256,256]
//
// Composed 1D filters (x16), indexed [analysis][synthesis]:
//   (l,l): [1, 7, 7, 1]   (l,h): [1, 1,-1,-1]
//   (h,l): [1, 5,-5,-1]   (h,h): [1,-1,-1, 1]
// new_in[4*comp+ch](oy,ox) = (1/256) * sum_g s_g *
//     [y-filter(comp,gY) (x) x-filter(comp,gX)] . x[4g+ch][2oy-1..2oy+2][2ox-1..2ox+2]
// comp: 0=ll 1=lh 2=hl 3=hh ; g: 0=ll(+) 1=lh(-) 2=hl(-) 3=hh(+)

#define H_IN 512
#define W_IN 512
#define H_OUT 256
#define W_OUT 256
#define NB 8
#define C_MID 16
#define C_OUT 512

typedef float fx4 __attribute__((ext_vector_type(4)));

__device__ __forceinline__ float cL(int fsel, float a0, float a1, float a2, float a3) {
  // analysis = l; fsel 0 -> [1,7,7,1], 1 -> [1,1,-1,-1]
  return fsel == 0 ? (a0 + 7.f*a1 + 7.f*a2 + a3) : (a0 + a1 - a2 - a3);
}
__device__ __forceinline__ float cH(int fsel, float a0, float a1, float a2, float a3) {
  // analysis = h; fsel 0 -> [1,5,-5,-1], 1 -> [1,-1,-1,1]
  return fsel == 0 ? (a0 + 5.f*a1 - 5.f*a2 - a3) : (a0 - a1 - a2 + a3);
}

// Stage 1: x -> new_in. One thread computes 4 comps x 1 row x 4 cols (16
// outputs) for one (b, ch). UNCHANGED from round 3.
__global__ __launch_bounds__(256) void k_stage1(const float* __restrict__ x,
                                                float* __restrict__ nin) {
  const int t  = threadIdx.x;
  const int q  = t & 63;                       // output cols 4q..4q+3
  const int oy = blockIdx.x * 4 + (t >> 6);    // one output row (wave-uniform)
  const int bz = blockIdx.y;                   // b*4 + ch
  const int b = bz >> 2, ch = bz & 3;
  const int y0 = 2 * oy - 1;

  const float WL[2][4] = {{1.f, 7.f, 7.f, 1.f}, {1.f, 1.f, -1.f, -1.f}};
  const float WH[2][4] = {{1.f, 5.f, -5.f, -1.f}, {1.f, -1.f, -1.f, 1.f}};

  float acc[4][4];                             // [comp][xo]
#pragma unroll
  for (int i = 0; i < 4; ++i)
#pragma unroll
    for (int k = 0; k < 4; ++k) acc[i][k] = 0.f;

#pragma unroll
  for (int g = 0; g < 4; ++g) {
    const int gY = g & 1, gX = g >> 1;
    const float sg = (g == 1 || g == 2) ? -1.f : 1.f;
    const float* xp = x + (size_t)(b * 16 + g * 4 + ch) * (H_IN * W_IN);
#pragma unroll
    for (int p = 0; p < 4; ++p) {
      const int yy = y0 + p;
      if (yy < 0 || yy >= H_IN) continue;      // wave-uniform branch
      const float* row = xp + (size_t)yy * W_IN + 8 * q;
      float c[10];                             // cols 8q-1 .. 8q+8
      c[0] = (q > 0) ? row[-1] : 0.f;
      const fx4 m0 = *reinterpret_cast<const fx4*>(row);
      const fx4 m1 = *reinterpret_cast<const fx4*>(row + 4);
      c[1] = m0.x; c[2] = m0.y; c[3] = m0.z; c[4] = m0.w;
      c[5] = m1.x; c[6] = m1.y; c[7] = m1.z; c[8] = m1.w;
      c[9] = (q < 63) ? row[8] : 0.f;
      const float wl = sg * WL[gY][p];
      const float wh = sg * WH[gY][p];
#pragma unroll
      for (int xo = 0; xo < 4; ++xo) {
        const float a0 = c[2*xo], a1 = c[2*xo+1], a2 = c[2*xo+2], a3 = c[2*xo+3];
        const float vL = cL(gX, a0, a1, a2, a3);
        const float vH = cH(gX, a0, a1, a2, a3);
        acc[0][xo] = fmaf(wl, vL, acc[0][xo]);
        acc[1][xo] = fmaf(wh, vL, acc[1][xo]);
        acc[2][xo] = fmaf(wl, vH, acc[2][xo]);
        acc[3][xo] = fmaf(wh, vH, acc[3][xo]);
      }
    }
  }

  const float inv = 1.f / 256.f;
#pragma unroll
  for (int comp = 0; comp < 4; ++comp) {
    fx4 r;
    r.x = acc[comp][0] * inv; r.y = acc[comp][1] * inv;
    r.z = acc[comp][2] * inv; r.w = acc[comp][3] * inv;
    *reinterpret_cast<fx4*>(
        nin + ((size_t)(b * 16 + comp * 4 + ch) * H_OUT + oy) * W_OUT + 4 * q) = r;
  }
}

__device__ __forceinline__ fx4 vfma(fx4 v, float s, fx4 a) {
  a.x = fmaf(v.x, s, a.x); a.y = fmaf(v.y, s, a.y);
  a.z = fmaf(v.z, s, a.z); a.w = fmaf(v.w, s, a.w);
  return a;
}

// Stage 2: 1x1 conv 16->512 + bias + leakyrelu*sqrt2, channel-chunked 4-way.
// SINGLE CHANGE vs round 3: regular stores instead of nontemporal — testing
// whether the nt path is what caps effective write BW at ~4.8 TB/s.
__global__ __launch_bounds__(256) void k_stage2(const float* __restrict__ nin,
                                                const float* __restrict__ w,
                                                const float* __restrict__ bias,
                                                float* __restrict__ out) {
  __shared__ fx4 ws4[128 * 4];
  __shared__ float bs[128];
  const int t = threadIdx.x;
  const int chunk = blockIdx.z;                // 0..3 -> channels 128*chunk..+127
  const int obase = 128 * chunk;

  const fx4* w4 = reinterpret_cast<const fx4*>(w + (size_t)obase * 16);
  ws4[t]       = w4[t] * 0.25f;
  ws4[t + 256] = w4[t + 256] * 0.25f;
  if (t < 128) bs[t] = bias[obase + t];
  __syncthreads();

  const int by = blockIdx.x;                   // 0..63
  const int b  = blockIdx.y;                   // 0..7
  const int y  = 4 * by + (t >> 6);
  const int xq = (t & 63) * 4;

  const float* np = nin + ((size_t)(b * C_MID) * H_OUT + y) * W_OUT + xq;
  fx4 v[16];
#pragma unroll
  for (int c = 0; c < 16; ++c)
    v[c] = *reinterpret_cast<const fx4*>(np + (size_t)c * (H_OUT * W_OUT));

  float* op = out + ((size_t)(b * C_OUT + obase) * H_OUT + y) * W_OUT + xq;
  const float s2 = 1.41421356237309515f;
#pragma unroll 2
  for (int o = 0; o < 128; ++o) {
    const fx4 w0 = ws4[4*o], w1 = ws4[4*o+1], w2 = ws4[4*o+2], w3 = ws4[4*o+3];
    const float bo = bs[o];
    fx4 a; a.x = bo; a.y = bo; a.z = bo; a.w = bo;
    a = vfma(v[0],  w0.x, a); a = vfma(v[1],  w0.y, a);
    a = vfma(v[2],  w0.z, a); a = vfma(v[3],  w0.w, a);
    a = vfma(v[4],  w1.x, a); a = vfma(v[5],  w1.y, a);
    a = vfma(v[6],  w1.z, a); a = vfma(v[7],  w1.w, a);
    a = vfma(v[8],  w2.x, a); a = vfma(v[9],  w2.y, a);
    a = vfma(v[10], w2.z, a); a = vfma(v[11], w2.w, a);
    a = vfma(v[12], w3.x, a); a = vfma(v[13], w3.y, a);
    a = vfma(v[14], w3.z, a); a = vfma(v[15], w3.w, a);
    a.x = (a.x >= 0.f ? a.x : 0.2f * a.x) * s2;
    a.y = (a.y >= 0.f ? a.y : 0.2f * a.y) * s2;
    a.z = (a.z >= 0.f ? a.z : 0.2f * a.z) * s2;
    a.w = (a.w >= 0.f ? a.w : 0.2f * a.w) * s2;
    *reinterpret_cast<fx4*>(op + (size_t)o * (H_OUT * W_OUT)) = a;
  }
}

extern "C" void kernel_launch(void* const* d_in, const int* in_sizes, int n_in,
                              void* d_out, int out_size, void* d_ws, size_t ws_size,
                              hipStream_t stream) {
  const float* x    = (const float*)d_in[0];
  const float* w    = (const float*)d_in[1];
  const float* bias = (const float*)d_in[2];
  float* nin = (float*)d_out;                                       // output 0
  float* out = (float*)d_out + (size_t)NB * C_MID * H_OUT * W_OUT;  // output 1

  k_stage1<<<dim3(64, 32), dim3(256), 0, stream>>>(x, nin);
  k_stage2<<<dim3(64, 8, 4), dim3(256), 0, stream>>>(nin, w, bias, out);
}

// Round 5
// 267.548 us; speedup vs baseline: 1.0496x; 1.0496x over previous
//
#include <hip/hip_runtime.h>

// FromRGB fully fused:
//   x[8,16,512,512] --(IHT up2 + blur down2 + Haar down2 == one separable
//   4x4 stride-2 stencil)--> new_in[8,16,256,256]  (output 0, kept in regs)
//   --(1x1 conv 16->512 * 0.25, +bias, leakyrelu(0.2)*sqrt2)--> out[8,512,256,256]
//
// Composed 1D filters (x16), [analysis][synthesis]:
//   (l,l): [1, 7, 7, 1]   (l,h): [1, 1,-1,-1]
//   (h,l): [1, 5,-5,-1]   (h,h): [1,-1,-1, 1]
// new_in[4*comp+ch](oy,ox) = (1/256) * sum_g s_g *
//   [yfilt(comp,gY) (x) xfilt(comp,gX)] . x[4g+ch][2oy-1..2oy+2][2ox-1..2ox+2]
// comp: 0=ll 1=lh 2=hl 3=hh ; g: 0=ll(+) 1=lh(-) 2=hl(-) 3=hh(+)
//
// One block = 4 output rows x 256 cols of one image b. Each thread owns 4
// consecutive cols of one row: computes all 16 nin channels there (fx4
// acc[16], static indexing), stores nin, then conv from REGISTERS with
// weights in LDS -> 512 nt float4 stores. No nin round-trip, one dispatch.

#define H_IN 512
#define W_IN 512
#define H_OUT 256
#define W_OUT 256
#define NB 8
#define C_MID 16
#define C_OUT 512

typedef float fx4 __attribute__((ext_vector_type(4)));

__device__ __forceinline__ float cL(int fsel, float a0, float a1, float a2, float a3) {
  // analysis = l; fsel 0 -> [1,7,7,1], 1 -> [1,1,-1,-1]
  return fsel == 0 ? (a0 + 7.f*a1 + 7.f*a2 + a3) : (a0 + a1 - a2 - a3);
}
__device__ __forceinline__ float cH(int fsel, float a0, float a1, float a2, float a3) {
  // analysis = h; fsel 0 -> [1,5,-5,-1], 1 -> [1,-1,-1,1]
  return fsel == 0 ? (a0 + 5.f*a1 - 5.f*a2 - a3) : (a0 - a1 - a2 + a3);
}

__device__ __forceinline__ fx4 vfma(fx4 v, float s, fx4 a) {
  a.x = fmaf(v.x, s, a.x); a.y = fmaf(v.y, s, a.y);
  a.z = fmaf(v.z, s, a.z); a.w = fmaf(v.w, s, a.w);
  return a;
}

__global__ __launch_bounds__(256) void k_fused(const float* __restrict__ x,
                                               const float* __restrict__ w,
                                               const float* __restrict__ bias,
                                               float* __restrict__ nin,
                                               float* __restrict__ out) {
  __shared__ fx4 ws4[C_OUT * 4];   // 32 KB: w[o][c] * 0.25/256, fx4 over c
  __shared__ float bs[C_OUT];      // 2 KB
  const int t = threadIdx.x;

  // Cooperative weight/bias load — issued first so it hides under phase 1.
  const fx4* w4 = reinterpret_cast<const fx4*>(w);
  const float wscale = 0.25f * (1.f / 256.f);
#pragma unroll
  for (int i = 0; i < 8; ++i) ws4[t + 256 * i] = w4[t + 256 * i] * wscale;
  bs[t] = bias[t];
  bs[t + 256] = bias[t + 256];

  const int q = t & 63;                    // output cols 4q..4q+3
  const int y = blockIdx.x * 4 + (t >> 6); // output row (wave-uniform)
  const int b = blockIdx.y;                // image
  const int y0 = 2 * y - 1;

  const float WL[2][4] = {{1.f, 7.f, 7.f, 1.f}, {1.f, 1.f, -1.f, -1.f}};
  const float WH[2][4] = {{1.f, 5.f, -5.f, -1.f}, {1.f, -1.f, -1.f, 1.f}};

  // ---- Phase 1: stencil. acc[comp*4+ch][xo] = unscaled nin*256 ----
  fx4 acc[16];
#pragma unroll
  for (int c = 0; c < 16; ++c) acc[c] = (fx4){0.f, 0.f, 0.f, 0.f};

#pragma unroll
  for (int ch = 0; ch < 4; ++ch) {
#pragma unroll
    for (int g = 0; g < 4; ++g) {
      const int gY = g & 1, gX = g >> 1;
      const float sg = (g == 1 || g == 2) ? -1.f : 1.f;
      const float* xp = x + (size_t)(b * 16 + g * 4 + ch) * (H_IN * W_IN);
#pragma unroll
      for (int p = 0; p < 4; ++p) {
        const int yy = y0 + p;
        if (yy < 0 || yy >= H_IN) continue;  // wave-uniform branch
        const float* row = xp + (size_t)yy * W_IN + 8 * q;
        float c0 = (q > 0) ? row[-1] : 0.f;
        const fx4 m0 = *reinterpret_cast<const fx4*>(row);
        const fx4 m1 = *reinterpret_cast<const fx4*>(row + 4);
        const float c9 = (q < 63) ? row[8] : 0.f;
        const float cc[10] = {c0, m0.x, m0.y, m0.z, m0.w,
                              m1.x, m1.y, m1.z, m1.w, c9};
        const float wl = sg * WL[gY][p];
        const float wh = sg * WH[gY][p];
        fx4 vL, vH;
        vL.x = cL(gX, cc[0], cc[1], cc[2], cc[3]);
        vL.y = cL(gX, cc[2], cc[3], cc[4], cc[5]);
        vL.z = cL(gX, cc[4], cc[5], cc[6], cc[7]);
        vL.w = cL(gX, cc[6], cc[7], cc[8], cc[9]);
        vH.x = cH(gX, cc[0], cc[1], cc[2], cc[3]);
        vH.y = cH(gX, cc[2], cc[3], cc[4], cc[5]);
        vH.z = cH(gX, cc[4], cc[5], cc[6], cc[7]);
        vH.w = cH(gX, cc[6], cc[7], cc[8], cc[9]);
        acc[0 * 4 + ch] = vfma(vL, wl, acc[0 * 4 + ch]);
        acc[1 * 4 + ch] = vfma(vL, wh, acc[1 * 4 + ch]);
        acc[2 * 4 + ch] = vfma(vH, wl, acc[2 * 4 + ch]);
        acc[3 * 4 + ch] = vfma(vH, wh, acc[3 * 4 + ch]);
      }
    }
  }

  // nin (output 0): scaled by 1/256.
  const float inv = 1.f / 256.f;
#pragma unroll
  for (int c = 0; c < 16; ++c) {
    fx4 r;
    r.x = acc[c].x * inv; r.y = acc[c].y * inv;
    r.z = acc[c].z * inv; r.w = acc[c].w * inv;
    *reinterpret_cast<fx4*>(
        nin + ((size_t)(b * C_MID + c) * H_OUT + y) * W_OUT + 4 * q) = r;
  }

  __syncthreads();  // ws4/bs ready

  // ---- Phase 2: 1x1 conv from registers (weights carry the 1/256) ----
  float* op = out + ((size_t)(b * C_OUT) * H_OUT + y) * W_OUT + 4 * q;
  const float s2 = 1.41421356237309515f;
#pragma unroll 2
  for (int o = 0; o < C_OUT; ++o) {
    const fx4 w0 = ws4[4*o], w1 = ws4[4*o+1], w2 = ws4[4*o+2], w3 = ws4[4*o+3];
    const float bo = bs[o];
    fx4 a; a.x = bo; a.y = bo; a.z = bo; a.w = bo;
    a = vfma(acc[0],  w0.x, a); a = vfma(acc[1],  w0.y, a);
    a = vfma(acc[2],  w0.z, a); a = vfma(acc[3],  w0.w, a);
    a = vfma(acc[4],  w1.x, a); a = vfma(acc[5],  w1.y, a);
    a = vfma(acc[6],  w1.z, a); a = vfma(acc[7],  w1.w, a);
    a = vfma(acc[8],  w2.x, a); a = vfma(acc[9],  w2.y, a);
    a = vfma(acc[10], w2.z, a); a = vfma(acc[11], w2.w, a);
    a = vfma(acc[12], w3.x, a); a = vfma(acc[13], w3.y, a);
    a = vfma(acc[14], w3.z, a); a = vfma(acc[15], w3.w, a);
    a.x = (a.x >= 0.f ? a.x : 0.2f * a.x) * s2;
    a.y = (a.y >= 0.f ? a.y : 0.2f * a.y) * s2;
    a.z = (a.z >= 0.f ? a.z : 0.2f * a.z) * s2;
    a.w = (a.w >= 0.f ? a.w : 0.2f * a.w) * s2;
    __builtin_nontemporal_store(a,
        reinterpret_cast<fx4*>(op + (size_t)o * (H_OUT * W_OUT)));
  }
}

extern "C" void kernel_launch(void* const* d_in, const int* in_sizes, int n_in,
                              void* d_out, int out_size, void* d_ws, size_t ws_size,
                              hipStream_t stream) {
  const float* x    = (const float*)d_in[0];
  const float* w    = (const float*)d_in[1];
  const float* bias = (const float*)d_in[2];
  float* nin = (float*)d_out;                                       // output 0
  float* out = (float*)d_out + (size_t)NB * C_MID * H_OUT * W_OUT;  // output 1

  k_fused<<<dim3(64, 8), dim3(256), 0, stream>>>(x, w, bias, nin, out);
}

// Round 6
// 261.560 us; speedup vs baseline: 1.0736x; 1.0229x over previous
//
#include <hip/hip_runtime.h>

// FromRGB fully fused:
//   x[8,16,512,512] --(IHT up2 + blur down2 + Haar down2 == one separable
//   4x4 stride-2 stencil)--> new_in[8,16,256,256]  (output 0, kept in regs)
//   --(1x1 conv 16->512 * 0.25, +bias, leakyrelu(0.2)*sqrt2)--> out[8,512,256,256]
//
// Composed 1D filters (x16), [analysis][synthesis]:
//   (l,l): [1, 7, 7, 1]   (l,h): [1, 1,-1,-1]
//   (h,l): [1, 5,-5,-1]   (h,h): [1,-1,-1, 1]
// new_in[4*comp+ch](oy,ox) = (1/256) * sum_g s_g *
//   [yfilt(comp,gY) (x) xfilt(comp,gX)] . x[4g+ch][2oy-1..2oy+2][2ox-1..2ox+2]
//
// R6 change vs R5: phase 2 VALU thinned ~1.6x — sqrt2 folded into LDS
// weights/bias (leaky is positive-homogeneous), activation = max(u, 0.2u),
// conv arithmetic on float2 halves so it contracts to v_pk_fma_f32 /
// v_pk_max_f32; unroll 4; nin stores nontemporal. Discriminates
// VALU-feed-bound vs memory-wall.

#define H_IN 512
#define W_IN 512
#define H_OUT 256
#define W_OUT 256
#define NB 8
#define C_MID 16
#define C_OUT 512

typedef float fx4 __attribute__((ext_vector_type(4)));
typedef float fx2 __attribute__((ext_vector_type(2)));

__device__ __forceinline__ float cL(int fsel, float a0, float a1, float a2, float a3) {
  return fsel == 0 ? (a0 + 7.f*a1 + 7.f*a2 + a3) : (a0 + a1 - a2 - a3);
}
__device__ __forceinline__ float cH(int fsel, float a0, float a1, float a2, float a3) {
  return fsel == 0 ? (a0 + 5.f*a1 - 5.f*a2 - a3) : (a0 - a1 - a2 + a3);
}

__device__ __forceinline__ fx4 vfma(fx4 v, float s, fx4 a) {
  a.x = fmaf(v.x, s, a.x); a.y = fmaf(v.y, s, a.y);
  a.z = fmaf(v.z, s, a.z); a.w = fmaf(v.w, s, a.w);
  return a;
}
// float2 fma with scalar broadcast; -ffp-contract=fast turns this into
// llvm.fmuladd<2 x float> -> v_pk_fma_f32 on CDNA.
__device__ __forceinline__ fx2 vfma2(fx2 v, float s, fx2 a) {
  return v * (fx2){s, s} + a;
}

__global__ __launch_bounds__(256, 3) void k_fused(const float* __restrict__ x,
                                                  const float* __restrict__ w,
                                                  const float* __restrict__ bias,
                                                  float* __restrict__ nin,
                                                  float* __restrict__ out) {
  __shared__ fx4 ws4[C_OUT * 4];   // 32 KB: w[o][c] * sqrt2*0.25/256
  __shared__ float bs[C_OUT];      // 2 KB:  bias[o] * sqrt2
  const int t = threadIdx.x;

  const float s2 = 1.41421356237309515f;
  const fx4* w4 = reinterpret_cast<const fx4*>(w);
  const float wscale = s2 * 0.25f * (1.f / 256.f);
#pragma unroll
  for (int i = 0; i < 8; ++i) ws4[t + 256 * i] = w4[t + 256 * i] * wscale;
  bs[t] = bias[t] * s2;
  bs[t + 256] = bias[t + 256] * s2;

  const int q = t & 63;                    // output cols 4q..4q+3
  const int y = blockIdx.x * 4 + (t >> 6); // output row (wave-uniform)
  const int b = blockIdx.y;                // image
  const int y0 = 2 * y - 1;

  const float WL[2][4] = {{1.f, 7.f, 7.f, 1.f}, {1.f, 1.f, -1.f, -1.f}};
  const float WH[2][4] = {{1.f, 5.f, -5.f, -1.f}, {1.f, -1.f, -1.f, 1.f}};

  // ---- Phase 1: stencil (unchanged from R5). acc = nin*256 ----
  fx4 acc[16];
#pragma unroll
  for (int c = 0; c < 16; ++c) acc[c] = (fx4){0.f, 0.f, 0.f, 0.f};

#pragma unroll
  for (int ch = 0; ch < 4; ++ch) {
#pragma unroll
    for (int g = 0; g < 4; ++g) {
      const int gY = g & 1, gX = g >> 1;
      const float sg = (g == 1 || g == 2) ? -1.f : 1.f;
      const float* xp = x + (size_t)(b * 16 + g * 4 + ch) * (H_IN * W_IN);
#pragma unroll
      for (int p = 0; p < 4; ++p) {
        const int yy = y0 + p;
        if (yy < 0 || yy >= H_IN) continue;  // wave-uniform branch
        const float* row = xp + (size_t)yy * W_IN + 8 * q;
        float c0 = (q > 0) ? row[-1] : 0.f;
        const fx4 m0 = *reinterpret_cast<const fx4*>(row);
        const fx4 m1 = *reinterpret_cast<const fx4*>(row + 4);
        const float c9 = (q < 63) ? row[8] : 0.f;
        const float cc[10] = {c0, m0.x, m0.y, m0.z, m0.w,
                              m1.x, m1.y, m1.z, m1.w, c9};
        const float wl = sg * WL[gY][p];
        const float wh = sg * WH[gY][p];
        fx4 vL, vH;
        vL.x = cL(gX, cc[0], cc[1], cc[2], cc[3]);
        vL.y = cL(gX, cc[2], cc[3], cc[4], cc[5]);
        vL.z = cL(gX, cc[4], cc[5], cc[6], cc[7]);
        vL.w = cL(gX, cc[6], cc[7], cc[8], cc[9]);
        vH.x = cH(gX, cc[0], cc[1], cc[2], cc[3]);
        vH.y = cH(gX, cc[2], cc[3], cc[4], cc[5]);
        vH.z = cH(gX, cc[4], cc[5], cc[6], cc[7]);
        vH.w = cH(gX, cc[6], cc[7], cc[8], cc[9]);
        acc[0 * 4 + ch] = vfma(vL, wl, acc[0 * 4 + ch]);
        acc[1 * 4 + ch] = vfma(vL, wh, acc[1 * 4 + ch]);
        acc[2 * 4 + ch] = vfma(vH, wl, acc[2 * 4 + ch]);
        acc[3 * 4 + ch] = vfma(vH, wh, acc[3 * 4 + ch]);
      }
    }
  }

  // nin (output 0), scaled by 1/256, nontemporal (never re-read).
  const float inv = 1.f / 256.f;
#pragma unroll
  for (int c = 0; c < 16; ++c) {
    fx4 r;
    r.x = acc[c].x * inv; r.y = acc[c].y * inv;
    r.z = acc[c].z * inv; r.w = acc[c].w * inv;
    __builtin_nontemporal_store(r, reinterpret_cast<fx4*>(
        nin + ((size_t)(b * C_MID + c) * H_OUT + y) * W_OUT + 4 * q));
  }

  // Split acc into packed halves for v_pk math.
  fx2 alo[16], ahi[16];
#pragma unroll
  for (int c = 0; c < 16; ++c) {
    alo[c] = (fx2){acc[c].x, acc[c].y};
    ahi[c] = (fx2){acc[c].z, acc[c].w};
  }

  __syncthreads();  // ws4/bs ready

  // ---- Phase 2: 1x1 conv via packed fp32; weights carry sqrt2/1024 ----
  float* op = out + ((size_t)(b * C_OUT) * H_OUT + y) * W_OUT + 4 * q;
  const fx2 k02 = {0.2f, 0.2f};
#pragma unroll 4
  for (int o = 0; o < C_OUT; ++o) {
    const fx4 w0 = ws4[4*o], w1 = ws4[4*o+1], w2 = ws4[4*o+2], w3 = ws4[4*o+3];
    const float bo = bs[o];
    fx2 ulo = {bo, bo}, uhi = {bo, bo};
    ulo = vfma2(alo[0],  w0.x, ulo); uhi = vfma2(ahi[0],  w0.x, uhi);
    ulo = vfma2(alo[1],  w0.y, ulo); uhi = vfma2(ahi[1],  w0.y, uhi);
    ulo = vfma2(alo[2],  w0.z, ulo); uhi = vfma2(ahi[2],  w0.z, uhi);
    ulo = vfma2(alo[3],  w0.w, ulo); uhi = vfma2(ahi[3],  w0.w, uhi);
    ulo = vfma2(alo[4],  w1.x, ulo); uhi = vfma2(ahi[4],  w1.x, uhi);
    ulo = vfma2(alo[5],  w1.y, ulo); uhi = vfma2(ahi[5],  w1.y, uhi);
    ulo = vfma2(alo[6],  w1.z, ulo); uhi = vfma2(ahi[6],  w1.z, uhi);
    ulo = vfma2(alo[7],  w1.w, ulo); uhi = vfma2(ahi[7],  w1.w, uhi);
    ulo = vfma2(alo[8],  w2.x, ulo); uhi = vfma2(ahi[8],  w2.x, uhi);
    ulo = vfma2(alo[9],  w2.y, ulo); uhi = vfma2(ahi[9],  w2.y, uhi);
    ulo = vfma2(alo[10], w2.z, ulo); uhi = vfma2(ahi[10], w2.z, uhi);
    ulo = vfma2(alo[11], w2.w, ulo); uhi = vfma2(ahi[11], w2.w, uhi);
    ulo = vfma2(alo[12], w3.x, ulo); uhi = vfma2(ahi[12], w3.x, uhi);
    ulo = vfma2(alo[13], w3.y, ulo); uhi = vfma2(ahi[13], w3.y, uhi);
    ulo = vfma2(alo[14], w3.z, ulo); uhi = vfma2(ahi[14], w3.z, uhi);
    ulo = vfma2(alo[15], w3.w, ulo); uhi = vfma2(ahi[15], w3.w, uhi);
    // leaky*sqrt2 already folded: out = max(u, 0.2u)  (packed max)
    ulo = __builtin_elementwise_max(ulo, ulo * k02);
    uhi = __builtin_elementwise_max(uhi, uhi * k02);
    fx4 r; r.x = ulo.x; r.y = ulo.y; r.z = uhi.x; r.w = uhi.y;
    __builtin_nontemporal_store(r,
        reinterpret_cast<fx4*>(op + (size_t)o * (H_OUT * W_OUT)));
  }
}

extern "C" void kernel_launch(void* const* d_in, const int* in_sizes, int n_in,
                              void* d_out, int out_size, void* d_ws, size_t ws_size,
                              hipStream_t stream) {
  const float* x    = (const float*)d_in[0];
  const float* w    = (const float*)d_in[1];
  const float* bias = (const float*)d_in[2];
  float* nin = (float*)d_out;                                       // output 0
  float* out = (float*)d_out + (size_t)NB * C_MID * H_OUT * W_OUT;  // output 1

  k_fused<<<dim3(64, 8), dim3(256), 0, stream>>>(x, w, bias, nin, out);
}

// Round 7
// 249.096 us; speedup vs baseline: 1.1273x; 1.0500x over previous
//
#include <hip/hip_runtime.h>

// FromRGB fully fused:
//   x[8,16,512,512] --(IHT up2 + blur down2 + Haar down2 == one separable
//   4x4 stride-2 stencil)--> new_in[8,16,256,256]  (output 0, kept in regs)
//   --(1x1 conv 16->512 * 0.25, +bias, leakyrelu(0.2)*sqrt2)--> out[8,512,256,256]
//
// Composed 1D filters (x16), [analysis][synthesis]:
//   (l,l): [1, 7, 7, 1]   (l,h): [1, 1,-1,-1]
//   (h,l): [1, 5,-5,-1]   (h,h): [1,-1,-1, 1]
//
// R7 changes vs R6:
//  * Phase 2 weights via wave-uniform SCALAR loads (s_load broadcast) from a
//    d_ws-packed table instead of per-wave ds_read_b128 — frees the DS pipe
//    (~90us/CU aggregate) and removes all LDS (occupancy = VGPR-bound only).
//  * Phase 1 edge columns via __shfl from neighbor lanes (wave spans the full
//    row) — VMEM instrs halve: 2x b128 per row, no scalar edge loads.

#define H_IN 512
#define W_IN 512
#define H_OUT 256
#define W_OUT 256
#define NB 8
#define C_MID 16
#define C_OUT 512

typedef float fx4 __attribute__((ext_vector_type(4)));

__device__ __forceinline__ float cL(int fsel, float a0, float a1, float a2, float a3) {
  return fsel == 0 ? (a0 + 7.f*a1 + 7.f*a2 + a3) : (a0 + a1 - a2 - a3);
}
__device__ __forceinline__ float cH(int fsel, float a0, float a1, float a2, float a3) {
  return fsel == 0 ? (a0 + 5.f*a1 - 5.f*a2 - a3) : (a0 - a1 - a2 + a3);
}

__device__ __forceinline__ fx4 vfma(fx4 v, float s, fx4 a) {
  a.x = fmaf(v.x, s, a.x); a.y = fmaf(v.y, s, a.y);
  a.z = fmaf(v.z, s, a.z); a.w = fmaf(v.w, s, a.w);
  return a;
}

// Prep: pack scaled weights+bias into d_ws, 32-float (128 B) stride per o:
//   wpk[o*32 + c] = w[o][c] * sqrt2*0.25/256   (c = 0..15)
//   wpk[o*32 + 16] = bias[o] * sqrt2
// 512 threads, one o each. Runs every launch (deterministic, ~2 us).
__global__ __launch_bounds__(256) void k_prep(const float* __restrict__ w,
                                              const float* __restrict__ bias,
                                              float* __restrict__ wpk) {
  const int o = blockIdx.x * 256 + threadIdx.x;   // 0..511
  const float s2 = 1.41421356237309515f;
  const float wscale = s2 * 0.25f * (1.f / 256.f);
#pragma unroll
  for (int c = 0; c < 16; ++c) wpk[o * 32 + c] = w[o * 16 + c] * wscale;
  wpk[o * 32 + 16] = bias[o] * s2;
}

__global__ __launch_bounds__(256) void k_fused(const float* __restrict__ x,
                                               const float* __restrict__ wpk,
                                               float* __restrict__ nin,
                                               float* __restrict__ out) {
  const int t = threadIdx.x;
  const int q = t & 63;                    // output cols 4q..4q+3 (wave = full row)
  const int y = blockIdx.x * 4 + (t >> 6); // output row (wave-uniform)
  const int b = blockIdx.y;                // image
  const int y0 = 2 * y - 1;

  const float WL[2][4] = {{1.f, 7.f, 7.f, 1.f}, {1.f, 1.f, -1.f, -1.f}};
  const float WH[2][4] = {{1.f, 5.f, -5.f, -1.f}, {1.f, -1.f, -1.f, 1.f}};

  // ---- Phase 1: stencil. acc[comp*4+ch] = nin*256 for this thread's quad ----
  fx4 acc[16];
#pragma unroll
  for (int c = 0; c < 16; ++c) acc[c] = (fx4){0.f, 0.f, 0.f, 0.f};

#pragma unroll
  for (int ch = 0; ch < 4; ++ch) {
#pragma unroll
    for (int g = 0; g < 4; ++g) {
      const int gY = g & 1, gX = g >> 1;
      const float sg = (g == 1 || g == 2) ? -1.f : 1.f;
      const float* xp = x + (size_t)(b * 16 + g * 4 + ch) * (H_IN * W_IN);
#pragma unroll
      for (int p = 0; p < 4; ++p) {
        const int yy = y0 + p;
        if (yy < 0 || yy >= H_IN) continue;   // wave-uniform branch
        const float* row = xp + (size_t)yy * W_IN + 8 * q;
        const fx4 m0 = *reinterpret_cast<const fx4*>(row);
        const fx4 m1 = *reinterpret_cast<const fx4*>(row + 4);
        // Edge cols from neighbor lanes: col 8q-1 = lane(q-1).m1.w,
        // col 8q+8 = lane(q+1).m0.x. Lane q-1/q+1 is in the same wave.
        const float c0s = __shfl(m1.w, q - 1);
        const float c9s = __shfl(m0.x, q + 1);
        const float cc0 = (q > 0) ? c0s : 0.f;
        const float cc9 = (q < 63) ? c9s : 0.f;
        const float cc[10] = {cc0, m0.x, m0.y, m0.z, m0.w,
                              m1.x, m1.y, m1.z, m1.w, cc9};
        const float wl = sg * WL[gY][p];
        const float wh = sg * WH[gY][p];
        fx4 vL, vH;
        vL.x = cL(gX, cc[0], cc[1], cc[2], cc[3]);
        vL.y = cL(gX, cc[2], cc[3], cc[4], cc[5]);
        vL.z = cL(gX, cc[4], cc[5], cc[6], cc[7]);
        vL.w = cL(gX, cc[6], cc[7], cc[8], cc[9]);
        vH.x = cH(gX, cc[0], cc[1], cc[2], cc[3]);
        vH.y = cH(gX, cc[2], cc[3], cc[4], cc[5]);
        vH.z = cH(gX, cc[4], cc[5], cc[6], cc[7]);
        vH.w = cH(gX, cc[6], cc[7], cc[8], cc[9]);
        acc[0 * 4 + ch] = vfma(vL, wl, acc[0 * 4 + ch]);
        acc[1 * 4 + ch] = vfma(vL, wh, acc[1 * 4 + ch]);
        acc[2 * 4 + ch] = vfma(vH, wl, acc[2 * 4 + ch]);
        acc[3 * 4 + ch] = vfma(vH, wh, acc[3 * 4 + ch]);
      }
    }
  }

  // nin (output 0), scaled 1/256, nontemporal (never re-read).
  const float inv = 1.f / 256.f;
#pragma unroll
  for (int c = 0; c < 16; ++c) {
    fx4 r;
    r.x = acc[c].x * inv; r.y = acc[c].y * inv;
    r.z = acc[c].z * inv; r.w = acc[c].w * inv;
    __builtin_nontemporal_store(r, reinterpret_cast<fx4*>(
        nin + ((size_t)(b * C_MID + c) * H_OUT + y) * W_OUT + 4 * q));
  }

  // ---- Phase 2: 1x1 conv; weights via wave-uniform scalar loads ----
  // wpk index depends only on loop counter o -> uniform -> s_load broadcast.
  float* op = out + ((size_t)(b * C_OUT) * H_OUT + y) * W_OUT + 4 * q;
#pragma unroll 2
  for (int o = 0; o < C_OUT; ++o) {
    const float* __restrict__ wrow = wpk + (o << 5);
    const float bo = wrow[16];
    fx4 a; a.x = bo; a.y = bo; a.z = bo; a.w = bo;
#pragma unroll
    for (int c = 0; c < 16; ++c) a = vfma(acc[c], wrow[c], a);
    // sqrt2 folded into weights/bias: out = max(u, 0.2u)
    a.x = fmaxf(a.x, 0.2f * a.x);
    a.y = fmaxf(a.y, 0.2f * a.y);
    a.z = fmaxf(a.z, 0.2f * a.z);
    a.w = fmaxf(a.w, 0.2f * a.w);
    __builtin_nontemporal_store(a,
        reinterpret_cast<fx4*>(op + (size_t)o * (H_OUT * W_OUT)));
  }
}

extern "C" void kernel_launch(void* const* d_in, const int* in_sizes, int n_in,
                              void* d_out, int out_size, void* d_ws, size_t ws_size,
                              hipStream_t stream) {
  const float* x    = (const float*)d_in[0];
  const float* w    = (const float*)d_in[1];
  const float* bias = (const float*)d_in[2];
  float* nin = (float*)d_out;                                       // output 0
  float* out = (float*)d_out + (size_t)NB * C_MID * H_OUT * W_OUT;  // output 1
  float* wpk = (float*)d_ws;  // 512*32*4 B = 64 KB packed weight table

  k_prep<<<dim3(2), dim3(256), 0, stream>>>(w, bias, wpk);
  k_fused<<<dim3(64, 8), dim3(256), 0, stream>>>(x, wpk, nin, out);
}